// Round 3
// baseline (1368.400 us; speedup 1.0000x reference)
//
#include <hip/hip_runtime.h>
#include <math.h>

#define NPTS 8192
#define LGAB2 (-13.0f)   // log2(1/8192)
#define NWAVE 16         // waves per block (1024 threads)
#define MARGIN 20.0f     // chunk skip margin vs M_est (exponent units, base 2)

typedef __attribute__((ext_vector_type(2))) float f2;

__device__ __forceinline__ float fexp2(float x){
#if __has_builtin(__builtin_amdgcn_exp2f)
  return __builtin_amdgcn_exp2f(x);
#else
  return exp2f(x);
#endif
}
__device__ __forceinline__ f2 ffma2(f2 a, f2 b, f2 c){
  return __builtin_elementwise_fma(a, b, c);   // v_pk_fma_f32
}
__device__ __forceinline__ f2 fmax2(f2 a, f2 b){
  return __builtin_elementwise_max(a, b);      // v_pk_max_f32
}
__device__ __forceinline__ f2 splat2(float v){ f2 r; r.x = v; r.y = v; return r; }

// wave64 sum via DPP row ops (VALU pipe — NOT the DS pipe like __shfl).
// After row_shr 1,2,4,8 each lane holds its 16-row inclusive prefix;
// row_bcast:15 then row_bcast:31 accumulate across rows. Total in lane 63.
__device__ __forceinline__ float dpp_reduce_add(float x){
  int v = __builtin_bit_cast(int, x);
#define DPP_STEP(ctrl) { \
    int o = __builtin_amdgcn_update_dpp(0, v, ctrl, 0xF, 0xF, true); \
    float f = __builtin_bit_cast(float, v) + __builtin_bit_cast(float, o); \
    v = __builtin_bit_cast(int, f); }
  DPP_STEP(0x111)  // row_shr:1
  DPP_STEP(0x112)  // row_shr:2
  DPP_STEP(0x114)  // row_shr:4
  DPP_STEP(0x118)  // row_shr:8
  DPP_STEP(0x142)  // row_bcast:15
  DPP_STEP(0x143)  // row_bcast:31
#undef DPP_STEP
  return __builtin_bit_cast(float, v);
}

// ---------------- counting sort by 12-bit Morton key (16^3 cells) ------------
__global__ __launch_bounds__(1024) void ws_sort(
    const float* __restrict__ x, const float* __restrict__ y,
    unsigned* __restrict__ sidx)
{
  __shared__ unsigned hist[4096];
  __shared__ unsigned wtot[16];
  const float* p = blockIdx.x ? y : x;
  int tid = threadIdx.x;
  for (int i = tid; i < 4096; i += 1024) hist[i] = 0;
  __syncthreads();
  unsigned key[8];
  for (int t = 0; t < 8; ++t) {
    int i = tid + (t << 10);
    unsigned q0 = (unsigned)fminf(fmaxf(p[3*i  ] * 16.f, 0.f), 15.f);
    unsigned q1 = (unsigned)fminf(fmaxf(p[3*i+1] * 16.f, 0.f), 15.f);
    unsigned q2 = (unsigned)fminf(fmaxf(p[3*i+2] * 16.f, 0.f), 15.f);
    unsigned k = 0;
    #pragma unroll
    for (int bb = 0; bb < 4; ++bb)
      k |= (((q0 >> bb) & 1u) << (3*bb)) | (((q1 >> bb) & 1u) << (3*bb+1))
         | (((q2 >> bb) & 1u) << (3*bb+2));
    key[t] = k;
    atomicAdd(&hist[k], 1u);
  }
  __syncthreads();
  unsigned c0 = hist[4*tid], c1 = hist[4*tid+1], c2 = hist[4*tid+2], c3 = hist[4*tid+3];
  unsigned tsum = c0 + c1 + c2 + c3;
  int lane = tid & 63, wv = tid >> 6;
  unsigned inc = tsum;
  for (int d = 1; d < 64; d <<= 1) {
    unsigned o = __shfl_up(inc, d);
    if (lane >= d) inc += o;
  }
  if (lane == 63) wtot[wv] = inc;
  __syncthreads();
  unsigned woff = 0;
  for (int k = 0; k < wv; ++k) woff += wtot[k];
  unsigned base = woff + inc - tsum;
  hist[4*tid] = base; hist[4*tid+1] = base + c0;
  hist[4*tid+2] = base + c0 + c1; hist[4*tid+3] = base + c0 + c1 + c2;
  __syncthreads();
  for (int t = 0; t < 8; ++t) {
    int i = tid + (t << 10);
    unsigned pos = atomicAdd(&hist[key[t]], 1u);
    sidx[blockIdx.x * NPTS + pos] = i;
  }
}

// Fine column pack (sorted domain): per 2 columns, float4 (x0,x1,y0,y1) then
// float4 (z0,z1,w0,w1) where w = h-term (exponent units base 2).
// Coarse pack (after 4*NPTS float4): 512 centroid-columns per slot.
__global__ __launch_bounds__(256) void ws_setup(
    const float* __restrict__ x, const float* __restrict__ y,
    const unsigned* __restrict__ sidx,
    float4* __restrict__ xp, float4* __restrict__ yp,
    float4* __restrict__ colpack, float inv0ce)
{
  int t = blockIdx.x * 256 + threadIdx.x;
  if (t >= NPTS) return;
  int ox = sidx[t], oy = sidx[NPTS + t];
  float x0 = x[3*ox], x1 = x[3*ox+1], x2 = x[3*ox+2];
  float xs = x0*x0 + x1*x1 + x2*x2;
  float y0 = y[3*oy], y1 = y[3*oy+1], y2 = y[3*oy+2];
  float ys = y0*y0 + y1*y1 + y2*y2;
  xp[t] = make_float4(x0,x1,x2,xs);
  yp[t] = make_float4(y0,y1,y2,ys);
  float hx = LGAB2 - 0.5f*xs*inv0ce;
  float hy = LGAB2 - 0.5f*ys*inv0ce;
  int p = t >> 1, sub = t & 1;
  {
    float* c0 = (float*)(colpack + 0*NPTS);
    c0[p*8+sub] = y0; c0[p*8+2+sub] = y1; c0[p*8+4+sub] = y2; c0[p*8+6+sub] = hy;
    float* c3 = (float*)(colpack + 3*NPTS);
    c3[p*8+sub] = y0; c3[p*8+2+sub] = y1; c3[p*8+4+sub] = y2; c3[p*8+6+sub] = hy;
  }
  {
    float* c1 = (float*)(colpack + 1*NPTS);
    c1[p*8+sub] = x0; c1[p*8+2+sub] = x1; c1[p*8+4+sub] = x2; c1[p*8+6+sub] = hx;
    float* c2 = (float*)(colpack + 2*NPTS);
    c2[p*8+sub] = x0; c2[p*8+2+sub] = x1; c2[p*8+4+sub] = x2; c2[p*8+6+sub] = hx;
  }
}

// Per-16-pt cluster: bbox, centroid, and initial coarse pack (duals = 0).
__global__ __launch_bounds__(512) void ws_bbox(
    const float4* __restrict__ xp, const float4* __restrict__ yp,
    float4* __restrict__ bbox, float4* __restrict__ cent,
    float4* __restrict__ cc0, float inv0ce)
{
  int c = threadIdx.x;           // 0..511
  int set = blockIdx.x;
  const float4* pp = set ? yp : xp;
  float lx = 1e30f, ly = 1e30f, lz = 1e30f;
  float hxx = -1e30f, hyy = -1e30f, hzz = -1e30f;
  float sx = 0.f, sy = 0.f, sz = 0.f, hm = -3.0e38f;
  float hv[16];
  for (int k = 0; k < 16; ++k) {
    float4 v = pp[c*16+k];
    lx = fminf(lx, v.x); ly = fminf(ly, v.y); lz = fminf(lz, v.z);
    hxx = fmaxf(hxx, v.x); hyy = fmaxf(hyy, v.y); hzz = fmaxf(hzz, v.z);
    sx += v.x; sy += v.y; sz += v.z;
    float h = LGAB2 - 0.5f * v.w * inv0ce;
    hv[k] = h; hm = fmaxf(hm, h);
  }
  float se = 0.f;
  for (int k = 0; k < 16; ++k) se += fexp2(hv[k] - hm);
  float H = hm + log2f(se);
  bbox[(set*512+c)*2+0] = make_float4(lx, ly, lz, 0.f);
  bbox[(set*512+c)*2+1] = make_float4(hxx, hyy, hzz, 0.f);
  float cx = sx * 0.0625f, cy = sy * 0.0625f, cz = sz * 0.0625f;
  cent[set*512+c] = make_float4(cx, cy, cz, 0.f);
  int s1 = set ? 0 : 1, s2 = set ? 3 : 2;   // slots using this set as columns
  int p = c >> 1, sub = c & 1;
  float* a = (float*)(cc0 + (size_t)s1 * 512);
  a[p*8+sub] = cx; a[p*8+2+sub] = cy; a[p*8+4+sub] = cz; a[p*8+6+sub] = H;
  float* bq = (float*)(cc0 + (size_t)s2 * 512);
  bq[p*8+sub] = cx; bq[p*8+2+sub] = cy; bq[p*8+4+sub] = cz; bq[p*8+6+sub] = H;
}

// dmin^2 at 16-ROW-GROUP granularity.
__global__ __launch_bounds__(512) void ws_dmin(
    const float4* __restrict__ bbox, float* __restrict__ dmin)
{
  int b = blockIdx.x;
  int s = b >> 7, rb = b & 127;
  int c = threadIdx.x;
  int rset = (s == 0 || s == 2) ? 0 : 1;
  int cset = (s == 0 || s == 3) ? 1 : 0;
  float4 bl = bbox[(cset*512 + c)*2], bh = bbox[(cset*512 + c)*2+1];
  #pragma unroll
  for (int g = 0; g < 4; ++g) {
    float4 l = bbox[(rset*512 + 4*rb + g)*2];
    float4 h = bbox[(rset*512 + 4*rb + g)*2+1];
    float dx = fmaxf(0.f, fmaxf(l.x - bh.x, bl.x - h.x));
    float dy = fmaxf(0.f, fmaxf(l.y - bh.y, bl.y - h.y));
    float dz = fmaxf(0.f, fmaxf(l.z - bh.z, bl.z - h.z));
    dmin[(((size_t)s*512 + 4*rb + g) << 9) + c] = dx*dx + dy*dy + dz*dz;
  }
}

// One phase.
// mode 1: fine single pass, COLUMNS-IN-REGISTERS structure (R3):
//   each lane owns 8 contiguous columns (4 f2-packs) in VGPRs, pre-scaled by
//   ce; wave = 512 contiguous sorted columns; rows iterate serially with row
//   data via wave-uniform s_load (K$-resident 1KB/block) and c_r = hx - Mest
//   folded in (rowpack, written by previous phase's epilogue). Per-row
//   cross-lane sum via DPP (VALU pipe). Skip at (512-col slab x 16-row group)
//   granularity from hmS/dmin (same sound bound, conservative superset).
//   R2 diagnosis: per-pair broadcast of column data (scalar K$ or DS pipe)
//   was the wall (~55-60us); this removes broadcast from the inner loop.
// mode 2: coarse exact two-pass over 512 centroid-columns (eps > 0.15 regime).
// kind: 0 = assign (init), 1 = 0.5*(P+T) average, 2 = final (write Tfin)
__global__ __launch_bounds__(1024, 8) void ws_softmin(
    const float4* __restrict__ xp, const float4* __restrict__ yp,
    const float4* __restrict__ cps, float4* __restrict__ cpd,
    float4* __restrict__ rowpk,
    const float* __restrict__ dmin, const float* __restrict__ hmS,
    float* __restrict__ hmD,
    const float4* __restrict__ cent,
    float* __restrict__ P, float* __restrict__ Tfin,
    float ce, float eps_ln2, float inv_next_ce, float rho_next, int kind, int mode)
{
  int b = blockIdx.x;
  int s = b >> 7;
  int rb = b & 127;
  int rowbase = rb << 6;
  int tid = threadIdx.x;
  int lane = tid & 63;
  int w = __builtin_amdgcn_readfirstlane(tid >> 6);

  int rset = (s == 0 || s == 2) ? 0 : 1;
  const float4* rp = rset ? yp : xp;
  float4 rv = rp[rowbase + lane];
  float hx = -0.5f * rv.w * ce;
  int row = rowbase + lane;

  __shared__ float lm[NWAVE][64];
  __shared__ float lss[NWAVE][64];
  float myMest = 0.f;

  if (mode == 2) {
    // ---- coarse exact two-pass: 512 centroid-cols, 32 per wave ----
    float a0 = rv.x * ce, a1 = rv.y * ce, a2 = rv.z * ce;
    f2 A0 = splat2(a0), A1 = splat2(a1), A2 = splat2(a2);
    const float4* pwc = cps + 4*(size_t)NPTS + (size_t)s*512 + (w << 5);
    f2 mA = {-3.0e38f, -3.0e38f}, mB = mA;
    #pragma unroll
    for (int pb = 0; pb < 16; pb += 2) {
      float4 P0 = pwc[2*pb+0], Q0 = pwc[2*pb+1];
      float4 P1 = pwc[2*pb+2], Q1 = pwc[2*pb+3];
      f2 X0={P0.x,P0.y}, Y0={P0.z,P0.w}, Z0={Q0.x,Q0.y}, W0={Q0.z,Q0.w};
      f2 X1={P1.x,P1.y}, Y1={P1.z,P1.w}, Z1={Q1.x,Q1.y}, W1={Q1.z,Q1.w};
      f2 t0 = ffma2(A2, Z0, W0); t0 = ffma2(A1, Y0, t0); t0 = ffma2(A0, X0, t0);
      f2 t1 = ffma2(A2, Z1, W1); t1 = ffma2(A1, Y1, t1); t1 = ffma2(A0, X1, t1);
      mA = fmax2(mA, t0); mB = fmax2(mB, t1);
    }
    f2 mAB = fmax2(mA, mB);
    float m = fmaxf(mAB.x, mAB.y);
    f2 M2 = {m, m};
    f2 sA = {0.f,0.f}, sB = {0.f,0.f};
    #pragma unroll
    for (int pb = 0; pb < 16; pb += 2) {
      float4 P0 = pwc[2*pb+0], Q0 = pwc[2*pb+1];
      float4 P1 = pwc[2*pb+2], Q1 = pwc[2*pb+3];
      f2 X0={P0.x,P0.y}, Y0={P0.z,P0.w}, Z0={Q0.x,Q0.y}, W0={Q0.z,Q0.w};
      f2 X1={P1.x,P1.y}, Y1={P1.z,P1.w}, Z1={Q1.x,Q1.y}, W1={Q1.z,Q1.w};
      f2 u0 = ffma2(A2, Z0, W0 - M2); u0 = ffma2(A1, Y0, u0); u0 = ffma2(A0, X0, u0);
      f2 u1 = ffma2(A2, Z1, W1 - M2); u1 = ffma2(A1, Y1, u1); u1 = ffma2(A0, X1, u1);
      f2 e0, e1;
      e0.x = fexp2(u0.x); e0.y = fexp2(u0.y);
      e1.x = fexp2(u1.x); e1.y = fexp2(u1.y);
      sA += e0; sB += e1;
    }
    f2 sAB = sA + sB;
    lm[w][lane] = m;
    lss[w][lane] = sAB.x + sAB.y;
  } else {
    // ---- fine single pass, columns-in-registers ----
    const float4* rowq = rowpk + (size_t)s * NPTS + rowbase;
    float4 rw0 = rowq[lane];                   // per-lane: own row's pack
    float Mest = hx - rw0.w;                   // c_r = hx - Mest
    myMest = Mest;
    // per-16-row-group max of Mest -> thresholds
    float gm = Mest;
    #pragma unroll
    for (int d = 8; d >= 1; d >>= 1) gm = fmaxf(gm, __shfl_xor(gm, d));
    // slab live mask: 4 bits (one per 16-row group); OR over my 32 chunks
    unsigned live = 0u;
    int cchunk = (w << 5) + (lane & 31);
    float hmv = hmS[s*512 + cchunk];
    #pragma unroll
    for (int rg = 0; rg < 4; ++rg) {
      float thr = __shfl(gm, rg << 4) - MARGIN;
      float dm = dmin[(((size_t)s*512 + 4*rb + rg) << 9) + cchunk];
      bool pass = (lane < 32) && (hmv - 0.5f*ce*dm > thr);
      if (__ballot(pass)) live |= (1u << rg);
    }
    if (live == 0u) live = 0xFu;               // safety: never drop everything
    // load my 8 columns (4 f2-packs), pre-scale coords by ce
    const float4* cb = cps + (size_t)s * NPTS + ((size_t)w << 9) + ((size_t)lane << 3);
    f2 Xc[4], Yc[4], Zc[4], Hc4[4];
    f2 ce2 = splat2(ce);
    #pragma unroll
    for (int j = 0; j < 4; ++j) {
      float4 Pv = cb[2*j], Qv = cb[2*j+1];
      f2 xx = {Pv.x, Pv.y}, yy = {Pv.z, Pv.w}, zz = {Qv.x, Qv.y};
      Xc[j] = xx * ce2;
      Yc[j] = yy * ce2;
      Zc[j] = zz * ce2;
      Hc4[j].x = Qv.z; Hc4[j].y = Qv.w;
    }
    lss[w][lane] = 0.f;                        // pre-zero my wave's slots
    for (int rg = 0; rg < 4; ++rg) {
      if (!(live & (1u << rg))) continue;
      #pragma unroll 4
      for (int rr = 0; rr < 16; ++rr) {
        int r = (rg << 4) + rr;
        float4 rwv = rowq[r];                  // uniform -> s_load_dwordx4
        f2 rx = splat2(rwv.x), ry = splat2(rwv.y), rz = splat2(rwv.z);
        f2 cc = splat2(rwv.w);
        f2 acc = {0.f, 0.f};
        #pragma unroll
        for (int j = 0; j < 4; ++j) {
          f2 t = ffma2(Zc[j], rz, Hc4[j] + cc);
          t = ffma2(Yc[j], ry, t);
          t = ffma2(Xc[j], rx, t);
          f2 ev;
          ev.x = fexp2(t.x); ev.y = fexp2(t.y);
          acc += ev;
        }
        float tot = dpp_reduce_add(acc.x + acc.y);
        if (lane == 63) lss[w][r] = tot;
      }
    }
  }
  __syncthreads();

  if (tid < 64) {
    float L;
    if (mode == 1) {
      float S = 0.f;
      #pragma unroll
      for (int k = 0; k < NWAVE; ++k) S += lss[k][lane];
      S = fmaxf(S, 1e-30f);
      L = myMest + log2f(S);
    } else {
      float M = lm[0][lane];
      #pragma unroll
      for (int k = 1; k < NWAVE; ++k) M = fmaxf(M, lm[k][lane]);
      float S = 0.f;
      #pragma unroll
      for (int k = 0; k < NWAVE; ++k) S += lss[k][lane] * fexp2(lm[k][lane] - M);
      L = hx + M + log2f(S);
    }
    float T = -eps_ln2 * L;
    if (kind == 2) {
      Tfin[s * NPTS + row] = T;
    } else {
      float* Pr = P + s * NPTS;
      float Pn = (kind == 0) ? T : 0.5f * (Pr[row] + T);
      Pr[row] = Pn;
      int dst = (s == 0) ? 1 : ((s == 1) ? 0 : s);
      float hy = LGAB2 + (Pn - 0.5f * rv.w) * inv_next_ce;
      float* cd = (float*)(cpd + (size_t)dst * NPTS);
      int p = row >> 1, sub = row & 1;
      cd[p*8+sub]   = rv.x;
      cd[p*8+2+sub] = rv.y;
      cd[p*8+4+sub] = rv.z;
      cd[p*8+6+sub] = hy;
      // rowpack for next phase (this slot's rows, block-private):
      // c_r = hx_next - Mest_next;  Mest_next = rho_next*(L - LGAB2) + LGAB2
      float Mn = fmaf(L - LGAB2, rho_next, LGAB2);
      float cR = -0.5f * rv.w * inv_next_ce - Mn;
      rowpk[(size_t)s * NPTS + row] = make_float4(rv.x, rv.y, rv.z, cR);
      // Skip-bound table: MUST be LGAB2 + Pn*ce (R14 errata: max(h_j) is NOT
      // a valid bound — the -0.5|y|^2 cancels against the x.y cross term).
      float hN = fmaf(Pn, inv_next_ce, LGAB2);
      #pragma unroll
      for (int d = 8; d >= 1; d >>= 1) hN = fmaxf(hN, __shfl_xor(hN, d));
      if ((lane & 15) == 0) hmD[dst*512 + 4*rb + (lane >> 4)] = hN;
      // coarse pack for next phase: cluster LSE of hy over 16-lane group
      float mh = hy;
      #pragma unroll
      for (int d = 8; d >= 1; d >>= 1) mh = fmaxf(mh, __shfl_xor(mh, d));
      float se = fexp2(hy - mh);
      #pragma unroll
      for (int d = 8; d >= 1; d >>= 1) se += __shfl_xor(se, d);
      float Hcs = mh + log2f(se);
      if ((lane & 15) == 0) {
        int gc = 4*rb + (lane >> 4);
        float4 cv = cent[rset*512 + gc];
        float* cc2 = (float*)(cpd + 4*(size_t)NPTS + (size_t)dst * 512);
        int p2 = gc >> 1, sub2 = gc & 1;
        cc2[p2*8+sub2]   = cv.x;
        cc2[p2*8+2+sub2] = cv.y;
        cc2[p2*8+4+sub2] = cv.z;
        cc2[p2*8+6+sub2] = Hcs;
      }
    }
  }
}

// loss = mean(f_fin - p_fin) + mean(g_fin - q_fin), fp64 accumulation
__global__ __launch_bounds__(256) void ws_reduce(
    const float* __restrict__ Tfin, float* __restrict__ out)
{
  int tid = threadIdx.x;
  double acc = 0.0;
  for (int i = tid; i < NPTS; i += 256) {
    acc += (double)Tfin[0*NPTS+i] - (double)Tfin[2*NPTS+i]
         + (double)Tfin[1*NPTS+i] - (double)Tfin[3*NPTS+i];
  }
  __shared__ double sd[256];
  sd[tid] = acc; __syncthreads();
  for (int k = 128; k > 0; k >>= 1) {
    if (tid < k) sd[tid] += sd[tid + k];
    __syncthreads();
  }
  if (tid == 0) out[0] = (float)(sd[0] / (double)NPTS);
}

extern "C" void kernel_launch(void* const* d_in, const int* in_sizes, int n_in,
                              void* d_out, int out_size, void* d_ws, size_t ws_size,
                              hipStream_t stream)
{
  const float* x = (const float*)d_in[0];
  const float* y = (const float*)d_in[1];
  float* out = (float*)d_out;

  const size_t CPSZ = (size_t)4 * NPTS + 2048;   // fine + coarse pack (float4)
  char* wsp = (char*)d_ws;
  float4*   xp   = (float4*)wsp;   wsp += (size_t)NPTS * 16;
  float4*   yp   = (float4*)wsp;   wsp += (size_t)NPTS * 16;
  float4*   cpA  = (float4*)wsp;   wsp += CPSZ * 16;
  float4*   cpB  = (float4*)wsp;   wsp += CPSZ * 16;
  float4*   rowpk= (float4*)wsp;   wsp += (size_t)4 * NPTS * 16;  // 512 KB
  float*    P    = (float*)wsp;    wsp += (size_t)4 * NPTS * 4;
  float*    Tfin = (float*)wsp;    wsp += (size_t)4 * NPTS * 4;
  unsigned* sidx = (unsigned*)wsp; wsp += (size_t)2 * NPTS * 4;
  float*    hmA  = (float*)wsp;    wsp += (size_t)4 * 512 * 4;
  float*    hmB  = (float*)wsp;    wsp += (size_t)4 * 512 * 4;
  float4*   bbox = (float4*)wsp;   wsp += (size_t)2 * 512 * 2 * 16;
  float4*   cent = (float4*)wsp;   wsp += (size_t)2 * 512 * 16;
  float*    dmin = (float*)wsp;    wsp += (size_t)4 * 512 * 512 * 4;  // 4 MB

  // geomloss epsilon schedule (f64, exactly as Python builds it)
  double epss[64]; int n = 0;
  double e = 4.0;                       // DIAMETER**P
  const double r = 0.9 * 0.9;          // SCALING**P
  const double target = 0.01 * 0.01;   // BLUR**P
  while (e > target && n < 60) { epss[n++] = e; e *= r; }   // n == 51

  // Phase plan (identical to the 1128 µs baseline — no error headroom for
  // schedule approximations): eps > 0.15 -> coarse512 (mode 2) stride-3;
  // 0.15 >= eps > 0.0025 -> fine stride-2; eps <= 0.0025 -> fine dense.
  // Final extrapolation at eps_final, fine.
  float feps[80]; int md[80]; int NPH = 0;
  feps[NPH] = (float)epss[0]; md[NPH] = 2; NPH++;          // init (coarse)
  {
    int k = 0;
    while (k < n) {
      int coarse = (epss[k] > 0.15);
      feps[NPH] = (float)epss[k]; md[NPH] = coarse ? 2 : 1; NPH++;
      k += coarse ? 3 : ((epss[k] > 0.0025) ? 2 : 1);
    }
  }
  feps[NPH] = 1e-4f; md[NPH] = 1; NPH++;                   // final

  const double L2E  = 1.4426950408889634;
  const double LN2d = 0.6931471805599453;

  float inv0ce = (float)(L2E / (double)feps[0]);
  ws_sort<<<2, 1024, 0, stream>>>(x, y, sidx);
  ws_setup<<<(NPTS + 255) / 256, 256, 0, stream>>>(x, y, sidx, xp, yp, cpA, inv0ce);
  ws_bbox<<<2, 512, 0, stream>>>(xp, yp, bbox, cent, cpA + 4*(size_t)NPTS, inv0ce);
  ws_dmin<<<512, 512, 0, stream>>>(bbox, dmin);

  for (int p = 0; p < NPH; ++p) {
    float epsf = feps[p];
    float ce = (float)(L2E / (double)epsf);
    float eps_ln2 = (float)((double)epsf * LN2d);
    float inv_next_ce = 0.f;
    float rho_next = 0.f;
    if (p < NPH - 1) {
      inv_next_ce = (float)(L2E / (double)feps[p+1]);
      rho_next = (float)((double)epsf / (double)feps[p+1]);
    }
    int kind = (p == 0) ? 0 : ((p == NPH - 1) ? 2 : 1);
    const float4* src = (p & 1) ? cpB : cpA;
    float4*       dst = (p & 1) ? cpA : cpB;
    const float*  hmS = (p & 1) ? hmB : hmA;
    float*        hmD = (p & 1) ? hmA : hmB;
    ws_softmin<<<512, 1024, 0, stream>>>(xp, yp, src, dst, rowpk, dmin, hmS, hmD,
                                         cent, P, Tfin,
                                         ce, eps_ln2, inv_next_ce, rho_next, kind, md[p]);
  }

  ws_reduce<<<1, 256, 0, stream>>>(Tfin, out);
}

// Round 4
// 897.065 us; speedup vs baseline: 1.5254x; 1.5254x over previous
//
#include <hip/hip_runtime.h>
#include <math.h>

#define NPTS 8192
#define LGAB2 (-13.0f)   // log2(1/8192)
#define NWAVE 16         // waves per block (1024 threads)
#define MARGIN 20.0f     // chunk skip margin vs M_est (exponent units, base 2)

typedef __attribute__((ext_vector_type(2))) float f2;
typedef __attribute__((ext_vector_type(4))) float f32x4;
typedef __attribute__((ext_vector_type(8))) short bf8;          // 8 bf16 (4 VGPR)
typedef __attribute__((ext_vector_type(8))) unsigned short us8;

__device__ __forceinline__ float fexp2(float x){
#if __has_builtin(__builtin_amdgcn_exp2f)
  return __builtin_amdgcn_exp2f(x);
#else
  return exp2f(x);
#endif
}
__device__ __forceinline__ f2 ffma2(f2 a, f2 b, f2 c){
  return __builtin_elementwise_fma(a, b, c);
}
__device__ __forceinline__ f2 fmax2(f2 a, f2 b){
  return __builtin_elementwise_max(a, b);
}
__device__ __forceinline__ f2 splat2(float v){ f2 r; r.x = v; r.y = v; return r; }

// bf16 round-to-nearest-even helpers + 3-way split (xh+xm+xl, residual 2^-27)
__device__ __forceinline__ unsigned short f2bf(float f){
  unsigned u = __builtin_bit_cast(unsigned, f);
  unsigned r = u + 0x7FFFu + ((u >> 16) & 1u);
  return (unsigned short)(r >> 16);
}
__device__ __forceinline__ float bf2f(unsigned short s){
  unsigned u = ((unsigned)s) << 16;
  return __builtin_bit_cast(float, u);
}
__device__ __forceinline__ void split3(float v, unsigned short& a,
                                       unsigned short& b, unsigned short& c){
  a = f2bf(v); float r = v - bf2f(a);
  b = f2bf(r); r -= bf2f(b);
  c = f2bf(r);
}

// sum over each 16-lane DPP row; lane 15 (mod 16) holds the row total
__device__ __forceinline__ float dpp_sum16(float x){
  int v = __builtin_bit_cast(int, x);
#define DPP_STEP(ctrl) { \
    int o = __builtin_amdgcn_update_dpp(0, v, ctrl, 0xF, 0xF, true); \
    float f = __builtin_bit_cast(float, v) + __builtin_bit_cast(float, o); \
    v = __builtin_bit_cast(int, f); }
  DPP_STEP(0x111)  // row_shr:1
  DPP_STEP(0x112)  // row_shr:2
  DPP_STEP(0x114)  // row_shr:4
  DPP_STEP(0x118)  // row_shr:8
#undef DPP_STEP
  return __builtin_bit_cast(float, v);
}

// ---------------- counting sort by 12-bit Morton key (16^3 cells) ------------
__global__ __launch_bounds__(1024) void ws_sort(
    const float* __restrict__ x, const float* __restrict__ y,
    unsigned* __restrict__ sidx)
{
  __shared__ unsigned hist[4096];
  __shared__ unsigned wtot[16];
  const float* p = blockIdx.x ? y : x;
  int tid = threadIdx.x;
  for (int i = tid; i < 4096; i += 1024) hist[i] = 0;
  __syncthreads();
  unsigned key[8];
  for (int t = 0; t < 8; ++t) {
    int i = tid + (t << 10);
    unsigned q0 = (unsigned)fminf(fmaxf(p[3*i  ] * 16.f, 0.f), 15.f);
    unsigned q1 = (unsigned)fminf(fmaxf(p[3*i+1] * 16.f, 0.f), 15.f);
    unsigned q2 = (unsigned)fminf(fmaxf(p[3*i+2] * 16.f, 0.f), 15.f);
    unsigned k = 0;
    #pragma unroll
    for (int bb = 0; bb < 4; ++bb)
      k |= (((q0 >> bb) & 1u) << (3*bb)) | (((q1 >> bb) & 1u) << (3*bb+1))
         | (((q2 >> bb) & 1u) << (3*bb+2));
    key[t] = k;
    atomicAdd(&hist[k], 1u);
  }
  __syncthreads();
  unsigned c0 = hist[4*tid], c1 = hist[4*tid+1], c2 = hist[4*tid+2], c3 = hist[4*tid+3];
  unsigned tsum = c0 + c1 + c2 + c3;
  int lane = tid & 63, wv = tid >> 6;
  unsigned inc = tsum;
  for (int d = 1; d < 64; d <<= 1) {
    unsigned o = __shfl_up(inc, d);
    if (lane >= d) inc += o;
  }
  if (lane == 63) wtot[wv] = inc;
  __syncthreads();
  unsigned woff = 0;
  for (int k = 0; k < wv; ++k) woff += wtot[k];
  unsigned base = woff + inc - tsum;
  hist[4*tid] = base; hist[4*tid+1] = base + c0;
  hist[4*tid+2] = base + c0 + c1; hist[4*tid+3] = base + c0 + c1 + c2;
  __syncthreads();
  for (int t = 0; t < 8; ++t) {
    int i = tid + (t << 10);
    unsigned pos = atomicAdd(&hist[key[t]], 1u);
    sidx[blockIdx.x * NPTS + pos] = i;
  }
}

// ---------------- B-pack static writer ----------------
// B-pack layout (shorts): [slot][ct(512)][g(4)*128][c(16)*8][j(8)]
// k-slot table p=g*8+j (A-side . B-side):
//  p0-2 xh_d.yh_d  p3-5 xm_d.yh_d  p6-8 xl_d.yh_d  p9-11 xh_d.ym_d
//  p12-14 xm_d.ym_d  p15-17 xh_d.yl_d  p18-20 1.h_split  p21-23 c_split.1
//  p24-31 zero. Any consistent A/B slot convention is valid (HW k-map is
//  symmetric between A and B); C layout col=lane&15,row=(lane>>4)*4+reg.
__device__ __forceinline__ void wbs(unsigned short* bp, int slot, int t,
    unsigned short h0, unsigned short h1, unsigned short h2,
    unsigned short m0, unsigned short m1, unsigned short m2,
    unsigned short l0, unsigned short l1, unsigned short l2)
{
  const unsigned short ONE = 0x3F80;
  size_t base = ((size_t)(slot*512 + (t >> 4))) * 512 + (size_t)(t & 15) * 8;
  us8 g0v = {h0,h1,h2,h0,h1,h2,h0,h1};
  us8 g1v = {h2,m0,m1,m2,m0,m1,m2,l0};
  us8 g2v = {l1,l2,0,0,0,ONE,ONE,ONE};   // h slots (j2..4) filled per phase
  us8 g3v = {0,0,0,0,0,0,0,0};
  *(us8*)(bp + base)        = g0v;
  *(us8*)(bp + base + 128)  = g1v;
  *(us8*)(bp + base + 256)  = g2v;
  *(us8*)(bp + base + 384)  = g3v;
}

__global__ __launch_bounds__(256) void ws_setup(
    const float* __restrict__ x, const float* __restrict__ y,
    const unsigned* __restrict__ sidx,
    float4* __restrict__ xp, float4* __restrict__ yp,
    unsigned short* __restrict__ bpA, unsigned short* __restrict__ bpB)
{
  int t = blockIdx.x * 256 + threadIdx.x;
  if (t >= NPTS) return;
  int ox = sidx[t], oy = sidx[NPTS + t];
  float x0 = x[3*ox], x1 = x[3*ox+1], x2 = x[3*ox+2];
  float xs = x0*x0 + x1*x1 + x2*x2;
  float y0 = y[3*oy], y1 = y[3*oy+1], y2 = y[3*oy+2];
  float ys = y0*y0 + y1*y1 + y2*y2;
  xp[t] = make_float4(x0,x1,x2,xs);
  yp[t] = make_float4(y0,y1,y2,ys);
  unsigned short a0,a1,a2,b0,b1,b2,c0,c1,c2;
  // x set -> columns of slots 1,2
  split3(x0,a0,b0,c0); split3(x1,a1,b1,c1); split3(x2,a2,b2,c2);
  wbs(bpA,1,t,a0,a1,a2,b0,b1,b2,c0,c1,c2);
  wbs(bpA,2,t,a0,a1,a2,b0,b1,b2,c0,c1,c2);
  wbs(bpB,1,t,a0,a1,a2,b0,b1,b2,c0,c1,c2);
  wbs(bpB,2,t,a0,a1,a2,b0,b1,b2,c0,c1,c2);
  // y set -> columns of slots 0,3
  split3(y0,a0,b0,c0); split3(y1,a1,b1,c1); split3(y2,a2,b2,c2);
  wbs(bpA,0,t,a0,a1,a2,b0,b1,b2,c0,c1,c2);
  wbs(bpA,3,t,a0,a1,a2,b0,b1,b2,c0,c1,c2);
  wbs(bpB,0,t,a0,a1,a2,b0,b1,b2,c0,c1,c2);
  wbs(bpB,3,t,a0,a1,a2,b0,b1,b2,c0,c1,c2);
}

// Per-16-pt cluster: bbox, centroid, and initial coarse pack (duals = 0).
__global__ __launch_bounds__(512) void ws_bbox(
    const float4* __restrict__ xp, const float4* __restrict__ yp,
    float4* __restrict__ bbox, float4* __restrict__ cent,
    float4* __restrict__ cc0, float inv0ce)
{
  int c = threadIdx.x;           // 0..511
  int set = blockIdx.x;
  const float4* pp = set ? yp : xp;
  float lx = 1e30f, ly = 1e30f, lz = 1e30f;
  float hxx = -1e30f, hyy = -1e30f, hzz = -1e30f;
  float sx = 0.f, sy = 0.f, sz = 0.f, hm = -3.0e38f;
  float hv[16];
  for (int k = 0; k < 16; ++k) {
    float4 v = pp[c*16+k];
    lx = fminf(lx, v.x); ly = fminf(ly, v.y); lz = fminf(lz, v.z);
    hxx = fmaxf(hxx, v.x); hyy = fmaxf(hyy, v.y); hzz = fmaxf(hzz, v.z);
    sx += v.x; sy += v.y; sz += v.z;
    float h = LGAB2 - 0.5f * v.w * inv0ce;
    hv[k] = h; hm = fmaxf(hm, h);
  }
  float se = 0.f;
  for (int k = 0; k < 16; ++k) se += fexp2(hv[k] - hm);
  float H = hm + log2f(se);
  bbox[(set*512+c)*2+0] = make_float4(lx, ly, lz, 0.f);
  bbox[(set*512+c)*2+1] = make_float4(hxx, hyy, hzz, 0.f);
  float cx = sx * 0.0625f, cy = sy * 0.0625f, cz = sz * 0.0625f;
  cent[set*512+c] = make_float4(cx, cy, cz, 0.f);
  int s1 = set ? 0 : 1, s2 = set ? 3 : 2;   // slots using this set as columns
  int p = c >> 1, sub = c & 1;
  float* a = (float*)(cc0 + (size_t)s1 * 512);
  a[p*8+sub] = cx; a[p*8+2+sub] = cy; a[p*8+4+sub] = cz; a[p*8+6+sub] = H;
  float* bq = (float*)(cc0 + (size_t)s2 * 512);
  bq[p*8+sub] = cx; bq[p*8+2+sub] = cy; bq[p*8+4+sub] = cz; bq[p*8+6+sub] = H;
}

// dmin^2 at 16-ROW-GROUP granularity.
__global__ __launch_bounds__(512) void ws_dmin(
    const float4* __restrict__ bbox, float* __restrict__ dmin)
{
  int b = blockIdx.x;
  int s = b >> 7, rb = b & 127;
  int c = threadIdx.x;
  int rset = (s == 0 || s == 2) ? 0 : 1;
  int cset = (s == 0 || s == 3) ? 1 : 0;
  float4 bl = bbox[(cset*512 + c)*2], bh = bbox[(cset*512 + c)*2+1];
  #pragma unroll
  for (int g = 0; g < 4; ++g) {
    float4 l = bbox[(rset*512 + 4*rb + g)*2];
    float4 h = bbox[(rset*512 + 4*rb + g)*2+1];
    float dx = fmaxf(0.f, fmaxf(l.x - bh.x, bl.x - h.x));
    float dy = fmaxf(0.f, fmaxf(l.y - bh.y, bl.y - h.y));
    float dz = fmaxf(0.f, fmaxf(l.z - bh.z, bl.z - h.z));
    dmin[(((size_t)s*512 + 4*rb + g) << 9) + c] = dx*dx + dy*dy + dz*dz;
  }
}

// One phase.
// mode 1: fine single pass via MFMA (R4): u = ce*x.y + h_j + (hx - Mest) is
//   computed 16x16-tile-at-a-time by mfma_f32_16x16x32_bf16 with bf16
//   triple-split operands (A-pack rows written per phase by epilogue; B-pack
//   cols: static y splits + per-phase h splits). VALU does only exp2+acc.
//   Skip at (16-col x 16-row) granularity from hmS/dmin (exact exists-row
//   semantics via group-min thresholds); ct ownership interleaved mod 16.
// mode 2: coarse exact two-pass over 512 centroid-columns (eps > 0.15 regime).
// kind: 0 = assign (init), 1 = 0.5*(P+T) average, 2 = final (write Tfin)
__global__ __launch_bounds__(1024, 4) void ws_softmin(
    const float4* __restrict__ xp, const float4* __restrict__ yp,
    unsigned short* __restrict__ apack,
    const unsigned short* __restrict__ bpS, unsigned short* __restrict__ bpD,
    const float4* __restrict__ ccS, float4* __restrict__ ccD,
    const float* __restrict__ dmin, const float* __restrict__ hmS,
    float* __restrict__ hmD, float* __restrict__ Mw,
    const float4* __restrict__ cent,
    float* __restrict__ P, float* __restrict__ Tfin,
    float ce, float eps_ln2, float inv_next_ce, float rho_next, int kind, int mode)
{
  int b = blockIdx.x;
  int s = b >> 7;
  int rb = b & 127;
  int rowbase = rb << 6;
  int tid = threadIdx.x;
  int lane = tid & 63;
  int w = __builtin_amdgcn_readfirstlane(tid >> 6);

  int rset = (s == 0 || s == 2) ? 0 : 1;
  const float4* rp = rset ? yp : xp;
  float4 rv = rp[rowbase + lane];
  float hx = -0.5f * rv.w * ce;
  int row = rowbase + lane;

  __shared__ float lm[NWAVE][64];
  __shared__ float lss[NWAVE][64];
  float myMest = 0.f;

  if (mode == 2) {
    // ---- coarse exact two-pass: 512 centroid-cols, 32 per wave ----
    float a0 = rv.x * ce, a1 = rv.y * ce, a2 = rv.z * ce;
    f2 A0 = splat2(a0), A1 = splat2(a1), A2 = splat2(a2);
    const float4* pwc = ccS + (size_t)s*512 + (w << 5);
    f2 mA = {-3.0e38f, -3.0e38f}, mB = mA;
    #pragma unroll
    for (int pb = 0; pb < 16; pb += 2) {
      float4 P0 = pwc[2*pb+0], Q0 = pwc[2*pb+1];
      float4 P1 = pwc[2*pb+2], Q1 = pwc[2*pb+3];
      f2 X0={P0.x,P0.y}, Y0={P0.z,P0.w}, Z0={Q0.x,Q0.y}, W0={Q0.z,Q0.w};
      f2 X1={P1.x,P1.y}, Y1={P1.z,P1.w}, Z1={Q1.x,Q1.y}, W1={Q1.z,Q1.w};
      f2 t0 = ffma2(A2, Z0, W0); t0 = ffma2(A1, Y0, t0); t0 = ffma2(A0, X0, t0);
      f2 t1 = ffma2(A2, Z1, W1); t1 = ffma2(A1, Y1, t1); t1 = ffma2(A0, X1, t1);
      mA = fmax2(mA, t0); mB = fmax2(mB, t1);
    }
    f2 mAB = fmax2(mA, mB);
    float m = fmaxf(mAB.x, mAB.y);
    f2 M2 = {m, m};
    f2 sA = {0.f,0.f}, sB = {0.f,0.f};
    #pragma unroll
    for (int pb = 0; pb < 16; pb += 2) {
      float4 P0 = pwc[2*pb+0], Q0 = pwc[2*pb+1];
      float4 P1 = pwc[2*pb+2], Q1 = pwc[2*pb+3];
      f2 X0={P0.x,P0.y}, Y0={P0.z,P0.w}, Z0={Q0.x,Q0.y}, W0={Q0.z,Q0.w};
      f2 X1={P1.x,P1.y}, Y1={P1.z,P1.w}, Z1={Q1.x,Q1.y}, W1={Q1.z,Q1.w};
      f2 u0 = ffma2(A2, Z0, W0 - M2); u0 = ffma2(A1, Y0, u0); u0 = ffma2(A0, X0, u0);
      f2 u1 = ffma2(A2, Z1, W1 - M2); u1 = ffma2(A1, Y1, u1); u1 = ffma2(A0, X1, u1);
      f2 e0, e1;
      e0.x = fexp2(u0.x); e0.y = fexp2(u0.y);
      e1.x = fexp2(u1.x); e1.y = fexp2(u1.y);
      sA += e0; sB += e1;
    }
    f2 sAB = sA + sB;
    lm[w][lane] = m;
    lss[w][lane] = sAB.x + sAB.y;
  } else {
    // ---- fine single pass, MFMA ----
    float MestL = Mw[(size_t)s * NPTS + rowbase + lane];
    myMest = MestL;
    // per-16-row-group MIN of Mest (exists-row skip semantics)
    float gmn = MestL;
    #pragma unroll
    for (int d = 8; d >= 1; d >>= 1) gmn = fminf(gmn, __shfl_xor(gmn, d));
    float thr0 = __shfl(gmn,  0) - MARGIN;
    float thr1 = __shfl(gmn, 16) - MARGIN;
    float thr2 = __shfl(gmn, 32) - MARGIN;
    float thr3 = __shfl(gmn, 48) - MARGIN;
    // masks: bit i of m[rt] -> ct = w + 16*i live for row-tile rt
    int il = lane & 31;
    int ctl = w + (il << 4);
    float hmv = hmS[s*512 + ctl];
    unsigned m0x, m1x, m2x, m3x;
    {
      float dm0 = dmin[(((size_t)s*512 + 4*rb + 0) << 9) + ctl];
      float dm1 = dmin[(((size_t)s*512 + 4*rb + 1) << 9) + ctl];
      float dm2 = dmin[(((size_t)s*512 + 4*rb + 2) << 9) + ctl];
      float dm3 = dmin[(((size_t)s*512 + 4*rb + 3) << 9) + ctl];
      bool lo = (lane < 32);
      m0x = (unsigned)__ballot(lo && (hmv - 0.5f*ce*dm0 > thr0));
      m1x = (unsigned)__ballot(lo && (hmv - 0.5f*ce*dm1 > thr1));
      m2x = (unsigned)__ballot(lo && (hmv - 0.5f*ce*dm2 > thr2));
      m3x = (unsigned)__ballot(lo && (hmv - 0.5f*ce*dm3 > thr3));
      if (m0x == 0u) m0x = 0xFFFFFFFFu;
      if (m1x == 0u) m1x = 0xFFFFFFFFu;
      if (m2x == 0u) m2x = 0xFFFFFFFFu;
      if (m3x == 0u) m3x = 0xFFFFFFFFu;
    }
    unsigned msk[4] = {m0x, m1x, m2x, m3x};
    unsigned any = m0x | m1x | m2x | m3x;
    // A fragments: 4 row-tiles
    const unsigned short* apb = apack + (((size_t)s * NPTS + rowbase) << 5);
    bf8 af[4];
    #pragma unroll
    for (int rt = 0; rt < 4; ++rt)
      af[rt] = *(const bf8*)(apb + (((rt*16) + (lane & 15)) << 5) + ((lane >> 4) << 3));
    f32x4 acc[4];
    #pragma unroll
    for (int rt = 0; rt < 4; ++rt) acc[rt] = (f32x4){0.f,0.f,0.f,0.f};
    const f32x4 kZero = {0.f,0.f,0.f,0.f};
    const unsigned short* bpb = bpS + (((size_t)s) << 18);
    int goff = ((lane >> 4) << 7) + ((lane & 15) << 3);
    unsigned rem = any;
    int ic = __builtin_ctz(rem); rem &= rem - 1u;
    bf8 bc = *(const bf8*)(bpb + (size_t)(w + (ic << 4)) * 512 + goff);
    for (;;) {
      int in = -1; bf8 bn;
      if (rem) {
        in = __builtin_ctz(rem); rem &= rem - 1u;
        bn = *(const bf8*)(bpb + (size_t)(w + (in << 4)) * 512 + goff);
      }
      #pragma unroll
      for (int rt = 0; rt < 4; ++rt) {
        if ((msk[rt] >> ic) & 1u) {
          f32x4 d = __builtin_amdgcn_mfma_f32_16x16x32_bf16(af[rt], bc, kZero, 0, 0, 0);
          f32x4 e;
          e.x = fexp2(d.x); e.y = fexp2(d.y); e.z = fexp2(d.z); e.w = fexp2(d.w);
          acc[rt] += e;
        }
      }
      if (in < 0) break;
      ic = in; bc = bn;
    }
    // reduce: sum over the 16 lanes of each group (cols) -> per-row totals
    #pragma unroll
    for (int rt = 0; rt < 4; ++rt) {
      #pragma unroll
      for (int q = 0; q < 4; ++q) {
        float v = dpp_sum16(acc[rt][q]);
        if ((lane & 15) == 15)
          lss[w][rt*16 + ((lane >> 4) << 2) + q] = v;
      }
    }
  }
  __syncthreads();

  if (tid < 64) {
    float L;
    if (mode == 1) {
      float S = 0.f;
      #pragma unroll
      for (int k = 0; k < NWAVE; ++k) S += lss[k][lane];
      S = fmaxf(S, 1e-30f);
      L = myMest + log2f(S);
    } else {
      float M = lm[0][lane];
      #pragma unroll
      for (int k = 1; k < NWAVE; ++k) M = fmaxf(M, lm[k][lane]);
      float S = 0.f;
      #pragma unroll
      for (int k = 0; k < NWAVE; ++k) S += lss[k][lane] * fexp2(lm[k][lane] - M);
      L = hx + M + log2f(S);
    }
    float T = -eps_ln2 * L;
    if (kind == 2) {
      Tfin[s * NPTS + row] = T;
    } else {
      float* Pr = P + s * NPTS;
      float Pn = (kind == 0) ? T : 0.5f * (Pr[row] + T);
      Pr[row] = Pn;
      int dst = (s == 0) ? 1 : ((s == 1) ? 0 : s);
      // h for dst-slot columns (3-way split into B-pack h slots)
      float hy = LGAB2 + (Pn - 0.5f * rv.w) * inv_next_ce;
      {
        unsigned short hh, hmm, hl;
        split3(hy, hh, hmm, hl);
        size_t hb = ((size_t)(dst*512 + (row >> 4))) * 512 + 256 + (size_t)(row & 15) * 8;
        bpD[hb + 2] = hh; bpD[hb + 3] = hmm; bpD[hb + 4] = hl;
      }
      // A-pack row record for own slot's next phase + Mw (= next Mest)
      float Mn = fmaf(L - LGAB2, rho_next, LGAB2);
      Mw[(size_t)s * NPTS + row] = Mn;
      {
        float cen = inv_next_ce;
        unsigned short a0h,a0m,a0l,a1h,a1m,a1l,a2h,a2m,a2l,ch,cm,cl;
        split3(rv.x * cen, a0h, a0m, a0l);
        split3(rv.y * cen, a1h, a1m, a1l);
        split3(rv.z * cen, a2h, a2m, a2l);
        float cr = (-0.5f * rv.w * cen) - Mn;
        split3(cr, ch, cm, cl);
        const unsigned short ONE = 0x3F80;
        us8 A0 = {a0h,a1h,a2h,a0m,a1m,a2m,a0l,a1l};
        us8 A1 = {a2l,a0h,a1h,a2h,a0m,a1m,a2m,a0h};
        us8 A2 = {a1h,a2h,ONE,ONE,ONE,ch,cm,cl};
        us8 A3 = {0,0,0,0,0,0,0,0};
        unsigned short* ap = apack + (((size_t)s * NPTS + row) << 5);
        *(us8*)(ap)      = A0;
        *(us8*)(ap + 8)  = A1;
        *(us8*)(ap + 16) = A2;
        *(us8*)(ap + 24) = A3;
      }
      // Skip-bound table: MUST be LGAB2 + Pn*ce (R14 errata: max(h_j) is NOT
      // a valid bound — the -0.5|y|^2 cancels against the x.y cross term).
      float hN = fmaf(Pn, inv_next_ce, LGAB2);
      #pragma unroll
      for (int d = 8; d >= 1; d >>= 1) hN = fmaxf(hN, __shfl_xor(hN, d));
      if ((lane & 15) == 0) hmD[dst*512 + 4*rb + (lane >> 4)] = hN;
      // coarse pack for next phase: cluster LSE of hy over 16-lane group
      float mh = hy;
      #pragma unroll
      for (int d = 8; d >= 1; d >>= 1) mh = fmaxf(mh, __shfl_xor(mh, d));
      float se = fexp2(hy - mh);
      #pragma unroll
      for (int d = 8; d >= 1; d >>= 1) se += __shfl_xor(se, d);
      float Hcs = mh + log2f(se);
      if ((lane & 15) == 0) {
        int gc = 4*rb + (lane >> 4);
        float4 cv = cent[rset*512 + gc];
        float* cc2 = (float*)(ccD + (size_t)dst * 512);
        int p2 = gc >> 1, sub2 = gc & 1;
        cc2[p2*8+sub2]   = cv.x;
        cc2[p2*8+2+sub2] = cv.y;
        cc2[p2*8+4+sub2] = cv.z;
        cc2[p2*8+6+sub2] = Hcs;
      }
    }
  }
}

// loss = mean(f_fin - p_fin) + mean(g_fin - q_fin), fp64 accumulation
__global__ __launch_bounds__(256) void ws_reduce(
    const float* __restrict__ Tfin, float* __restrict__ out)
{
  int tid = threadIdx.x;
  double acc = 0.0;
  for (int i = tid; i < NPTS; i += 256) {
    acc += (double)Tfin[0*NPTS+i] - (double)Tfin[2*NPTS+i]
         + (double)Tfin[1*NPTS+i] - (double)Tfin[3*NPTS+i];
  }
  __shared__ double sd[256];
  sd[tid] = acc; __syncthreads();
  for (int k = 128; k > 0; k >>= 1) {
    if (tid < k) sd[tid] += sd[tid + k];
    __syncthreads();
  }
  if (tid == 0) out[0] = (float)(sd[0] / (double)NPTS);
}

extern "C" void kernel_launch(void* const* d_in, const int* in_sizes, int n_in,
                              void* d_out, int out_size, void* d_ws, size_t ws_size,
                              hipStream_t stream)
{
  const float* x = (const float*)d_in[0];
  const float* y = (const float*)d_in[1];
  float* out = (float*)d_out;

  char* wsp = (char*)d_ws;
  float4*   xp   = (float4*)wsp;   wsp += (size_t)NPTS * 16;
  float4*   yp   = (float4*)wsp;   wsp += (size_t)NPTS * 16;
  unsigned short* apack = (unsigned short*)wsp; wsp += (size_t)4 * NPTS * 64;  // 2 MB
  unsigned short* bpA   = (unsigned short*)wsp; wsp += (size_t)4 * 512 * 1024; // 2 MB
  unsigned short* bpB   = (unsigned short*)wsp; wsp += (size_t)4 * 512 * 1024; // 2 MB
  float4*   ccA  = (float4*)wsp;   wsp += (size_t)4 * 512 * 16;
  float4*   ccB  = (float4*)wsp;   wsp += (size_t)4 * 512 * 16;
  float*    P    = (float*)wsp;    wsp += (size_t)4 * NPTS * 4;
  float*    Tfin = (float*)wsp;    wsp += (size_t)4 * NPTS * 4;
  unsigned* sidx = (unsigned*)wsp; wsp += (size_t)2 * NPTS * 4;
  float*    Mw   = (float*)wsp;    wsp += (size_t)4 * NPTS * 4;
  float*    hmA  = (float*)wsp;    wsp += (size_t)4 * 512 * 4;
  float*    hmB  = (float*)wsp;    wsp += (size_t)4 * 512 * 4;
  float4*   bbox = (float4*)wsp;   wsp += (size_t)2 * 512 * 2 * 16;
  float4*   cent = (float4*)wsp;   wsp += (size_t)2 * 512 * 16;
  float*    dmin = (float*)wsp;    wsp += (size_t)4 * 512 * 512 * 4;  // 4 MB

  // geomloss epsilon schedule (f64, exactly as Python builds it)
  double epss[64]; int n = 0;
  double e = 4.0;                       // DIAMETER**P
  const double r = 0.9 * 0.9;          // SCALING**P
  const double target = 0.01 * 0.01;   // BLUR**P
  while (e > target && n < 60) { epss[n++] = e; e *= r; }   // n == 51

  // Phase plan (identical to the 1128 µs baseline — no error headroom for
  // schedule approximations): eps > 0.15 -> coarse512 (mode 2) stride-3;
  // 0.15 >= eps > 0.0025 -> fine stride-2; eps <= 0.0025 -> fine dense.
  // Final extrapolation at eps_final, fine.
  float feps[80]; int md[80]; int NPH = 0;
  feps[NPH] = (float)epss[0]; md[NPH] = 2; NPH++;          // init (coarse)
  {
    int k = 0;
    while (k < n) {
      int coarse = (epss[k] > 0.15);
      feps[NPH] = (float)epss[k]; md[NPH] = coarse ? 2 : 1; NPH++;
      k += coarse ? 3 : ((epss[k] > 0.0025) ? 2 : 1);
    }
  }
  feps[NPH] = 1e-4f; md[NPH] = 1; NPH++;                   // final

  const double L2E  = 1.4426950408889634;
  const double LN2d = 0.6931471805599453;

  float inv0ce = (float)(L2E / (double)feps[0]);
  ws_sort<<<2, 1024, 0, stream>>>(x, y, sidx);
  ws_setup<<<(NPTS + 255) / 256, 256, 0, stream>>>(x, y, sidx, xp, yp, bpA, bpB);
  ws_bbox<<<2, 512, 0, stream>>>(xp, yp, bbox, cent, ccA, inv0ce);
  ws_dmin<<<512, 512, 0, stream>>>(bbox, dmin);

  for (int p = 0; p < NPH; ++p) {
    float epsf = feps[p];
    float ce = (float)(L2E / (double)epsf);
    float eps_ln2 = (float)((double)epsf * LN2d);
    float inv_next_ce = 0.f;
    float rho_next = 0.f;
    if (p < NPH - 1) {
      inv_next_ce = (float)(L2E / (double)feps[p+1]);
      rho_next = (float)((double)epsf / (double)feps[p+1]);
    }
    int kind = (p == 0) ? 0 : ((p == NPH - 1) ? 2 : 1);
    const unsigned short* bpS = (p & 1) ? bpB : bpA;
    unsigned short*       bpD_ = (p & 1) ? bpA : bpB;
    const float4* ccS = (p & 1) ? ccB : ccA;
    float4*       ccD = (p & 1) ? ccA : ccB;
    const float*  hmS = (p & 1) ? hmB : hmA;
    float*        hmD = (p & 1) ? hmA : hmB;
    ws_softmin<<<512, 1024, 0, stream>>>(xp, yp, apack, bpS, bpD_, ccS, ccD,
                                         dmin, hmS, hmD, Mw, cent, P, Tfin,
                                         ce, eps_ln2, inv_next_ce, rho_next,
                                         kind, md[p]);
  }

  ws_reduce<<<1, 256, 0, stream>>>(Tfin, out);
}